// Round 7
// baseline (6665.843 us; speedup 1.0000x reference)
//
#include <hip/hip_runtime.h>
#include <hip/hip_bf16.h>
#include <hip/hip_cooperative_groups.h>

namespace cg = cooperative_groups;

// Sizes (fixed by the problem)
#define B    64
#define P    196      // 14*14
#define DENC 2048
#define AA   512
#define EE   512
#define HH   512
#define VV   10000
#define LL   24
#define TT   23       // L-1

typedef unsigned short u16;
typedef unsigned int   u32;
typedef __bf16 bf16x8 __attribute__((ext_vector_type(8)));
typedef float  f32x4  __attribute__((ext_vector_type(4)));

__device__ __forceinline__ float wave_sum(float v) {
    #pragma unroll
    for (int o = 32; o > 0; o >>= 1) v += __shfl_xor(v, o, 64);
    return v;
}
__device__ __forceinline__ float sigmoidf(float x) {
    return 1.0f / (1.0f + __expf(-x));
}
// RNE fp32 -> bf16
__device__ __forceinline__ u16 f2b(float x) {
    u32 v = __float_as_uint(x); v += 0x7FFFu + ((v >> 16) & 1u); return (u16)(v >> 16);
}
__device__ __forceinline__ float b2f(u16 x) {
    return __uint_as_float(((u32)x) << 16);
}
__device__ __forceinline__ u32 pk2(float x, float y) {
    return (u32)f2b(x) | ((u32)f2b(y) << 16);
}

// ---------------- mean over P ----------------
__global__ __launch_bounds__(256) void mean_kernel(const float* __restrict__ enc, float* __restrict__ mean) {
    int b = blockIdx.y;
    int d = blockIdx.x * 256 + threadIdx.x;
    const float* e = enc + (long)b * P * DENC + d;
    float s = 0.f;
    #pragma unroll 4
    for (int p = 0; p < P; ++p) s += e[(long)p * DENC];
    mean[b * DENC + d] = s * (1.0f / (float)P);
}

// ---------------- h0/c0 init: wave per output ----------------
__global__ __launch_bounds__(256) void h0c0_kernel(const float* __restrict__ mean,
                                                   const float* __restrict__ W_h0, const float* __restrict__ b_h0,
                                                   const float* __restrict__ W_c0, const float* __restrict__ b_c0,
                                                   float* __restrict__ c, u16* __restrict__ h_bf) {
    int w = blockIdx.x * 4 + (threadIdx.x >> 6);   // 0..65535
    int lane = threadIdx.x & 63;
    int sel = w >> 15;            // 0: h0, 1: c0
    int r = w & 32767;
    int j = r >> 6, b = r & 63;
    const float4* mp = (const float4*)(mean + b * DENC);
    const float4* wp = (const float4*)((sel ? W_c0 : W_h0) + (long)j * DENC);
    float s = 0.f;
    for (int i = lane; i < DENC / 4; i += 64) {
        float4 x = mp[i], y = wp[i];
        s += x.x * y.x + x.y * y.y + x.z * y.z + x.w * y.w;
    }
    s = wave_sum(s);
    if (lane == 0) {
        float v = s + (sel ? b_c0[j] : b_h0[j]);
        if (sel) c[b * HH + j] = v;
        else     h_bf[b * HH + j] = f2b(v);
    }
}

// ---------------- prologue: bf16 conversions + weight rearrange + emb gather ----------------
__global__ __launch_bounds__(256) void prep_kernel(
    const float* __restrict__ enc, const float* __restrict__ W_ih, const float* __restrict__ W_hh,
    const float* __restrict__ b_ih, const float* __restrict__ b_hh,
    const float* __restrict__ emb, const int* __restrict__ cap,
    const float* __restrict__ W_hid, const float* __restrict__ W_beta,
    const float* __restrict__ b_hid, const float* __restrict__ b_beta,
    u16* __restrict__ enc_bf, u16* __restrict__ Wg_bf, u16* __restrict__ xemb, float* __restrict__ gbias,
    u16* __restrict__ Whg_bf, float* __restrict__ bhg)
{
    const long NU_ENC = 3211264;   // 64*196*2048/8
    const long NU_WG  = 786432;    // 2048*3072/8
    const long NU_XE  = 94208;     // 23*64*512/8
    const long NU_GB  = 256;       // 2048/8
    const long NU_WHG = 163840;    // 2560*512/8
    const long NU_BHG = 320;       // 2560/8
    const long NTOT = NU_ENC + NU_WG + NU_XE + NU_GB + NU_WHG + NU_BHG;
    long stride = (long)gridDim.x * 256;
    for (long u = (long)blockIdx.x * 256 + threadIdx.x; u < NTOT; u += stride) {
        if (u < NU_ENC) {
            const float* s = enc + u * 8;
            float4 a = *(const float4*)s, bb = *(const float4*)(s + 4);
            ((uint4*)enc_bf)[u] = make_uint4(pk2(a.x, a.y), pk2(a.z, a.w), pk2(bb.x, bb.y), pk2(bb.z, bb.w));
        } else if (u < NU_ENC + NU_WG) {
            long q = u - NU_ENC;
            long rw = q / 384;               // tile-row 0..2047 = wg*64 + r
            int k8 = (int)(q % 384) * 8;
            int wgt = (int)(rw >> 6), r = (int)(rw & 63);
            int gr = ((r >> 4) << 9) + (wgt << 4) + (r & 15);  // type*512 + wg*16 + jj
            const float* s = (k8 < 2560) ? (W_ih + (long)gr * 2560 + k8)
                                         : (W_hh + (long)gr * 512 + (k8 - 2560));
            float4 a = *(const float4*)s, bb = *(const float4*)(s + 4);
            ((uint4*)Wg_bf)[q] = make_uint4(pk2(a.x, a.y), pk2(a.z, a.w), pk2(bb.x, bb.y), pk2(bb.z, bb.w));
        } else if (u < NU_ENC + NU_WG + NU_XE) {
            long q = u - NU_ENC - NU_WG;
            int ku = (int)(q & 63);          // 8-elem chunk within 512
            int b  = (int)((q >> 6) & 63);
            int t  = (int)(q >> 12);         // /4096
            int tok = cap[b * LL + t];
            const float* s = emb + (long)tok * EE + ku * 8;
            float4 a = *(const float4*)s, bb = *(const float4*)(s + 4);
            ((uint4*)xemb)[q] = make_uint4(pk2(a.x, a.y), pk2(a.z, a.w), pk2(bb.x, bb.y), pk2(bb.z, bb.w));
        } else if (u < NU_ENC + NU_WG + NU_XE + NU_GB) {
            long q = u - NU_ENC - NU_WG - NU_XE;
            int i0 = (int)q * 8;
            #pragma unroll
            for (int j = 0; j < 8; ++j) gbias[i0 + j] = b_ih[i0 + j] + b_hh[i0 + j];
        } else if (u < NU_ENC + NU_WG + NU_XE + NU_GB + NU_WHG) {
            long q = u - NU_ENC - NU_WG - NU_XE - NU_GB;
            int rw = (int)(q >> 6);          // 0..2559
            int k8 = (int)(q & 63) * 8;
            const float* s = (rw < 512) ? (W_hid + (long)rw * HH + k8)
                                        : (W_beta + (long)(rw - 512) * HH + k8);
            float4 a = *(const float4*)s, bb = *(const float4*)(s + 4);
            ((uint4*)Whg_bf)[q] = make_uint4(pk2(a.x, a.y), pk2(a.z, a.w), pk2(bb.x, bb.y), pk2(bb.z, bb.w));
        } else {
            long q = u - NU_ENC - NU_WG - NU_XE - NU_GB - NU_WHG;
            int i0 = (int)q * 8;
            #pragma unroll
            for (int j = 0; j < 8; ++j) {
                int i = i0 + j;
                bhg[i] = (i < 512) ? b_hid[i] : b_beta[i - 512];
            }
        }
    }
}

// ---------------- bf16 MFMA GEMM: C = A(MxK) * B(NxK)^T + bias ----------------
template<bool ABF16, bool CBF16>
__global__ __launch_bounds__(256) void gemm_bf16_kernel(
    const void* __restrict__ Av, int lda,
    const float* __restrict__ Bm, int ldb,
    const float* __restrict__ bias,
    float* __restrict__ C, u16* __restrict__ Cbf, int ldc,
    int M, int N, int K,
    const int* __restrict__ caplen, int Tsteps)
{
    __shared__ __align__(16) u16 As[128 * 32];
    __shared__ __align__(16) u16 Bs[128 * 32];
    const int tid  = threadIdx.x;
    const int lane = tid & 63;
    const int w    = tid >> 6;
    const int wr   = w >> 1, wc = w & 1;
    const int bm = blockIdx.y * 128;
    const int bn = blockIdx.x * 128;

    f32x4 acc[4][4];
    #pragma unroll
    for (int m = 0; m < 4; ++m)
        #pragma unroll
        for (int n = 0; n < 4; ++n) acc[m][n] = (f32x4)0.f;

    const int srow = tid >> 1;
    const int scol = (tid & 1) * 16;
    long arow = bm + srow; if (arow >= M) arow = M - 1;
    long brow = bn + srow; if (brow >= N) brow = N - 1;
    const float* apf = ABF16 ? nullptr : (const float*)Av + arow * (long)lda + scol;
    const u16*   apb = ABF16 ? (const u16*)Av + arow * (long)lda + scol : nullptr;
    const float* bp  = Bm + brow * (long)ldb + scol;

    float4 ra[4], rb[4];
    uint4  rab[2];
    if (ABF16) { rab[0] = *(const uint4*)apb; rab[1] = *(const uint4*)(apb + 8); }
    else {
        #pragma unroll
        for (int i = 0; i < 4; ++i) ra[i] = *(const float4*)(apf + 4 * i);
    }
    #pragma unroll
    for (int i = 0; i < 4; ++i) rb[i] = *(const float4*)(bp + 4 * i);

    const int nk = K / 32;
    const int fr = lane & 15;
    const int kc = (lane >> 4) * 8;

    for (int kt = 0; kt < nk; ++kt) {
        uint4 pa0, pa1;
        if (ABF16) { pa0 = rab[0]; pa1 = rab[1]; }
        else {
            pa0 = make_uint4(pk2(ra[0].x, ra[0].y), pk2(ra[0].z, ra[0].w), pk2(ra[1].x, ra[1].y), pk2(ra[1].z, ra[1].w));
            pa1 = make_uint4(pk2(ra[2].x, ra[2].y), pk2(ra[2].z, ra[2].w), pk2(ra[3].x, ra[3].y), pk2(ra[3].z, ra[3].w));
        }
        uint4 pb0 = make_uint4(pk2(rb[0].x, rb[0].y), pk2(rb[0].z, rb[0].w), pk2(rb[1].x, rb[1].y), pk2(rb[1].z, rb[1].w));
        uint4 pb1 = make_uint4(pk2(rb[2].x, rb[2].y), pk2(rb[2].z, rb[2].w), pk2(rb[3].x, rb[3].y), pk2(rb[3].z, rb[3].w));
        __syncthreads();
        *(uint4*)&As[srow * 32 + scol]     = pa0;
        *(uint4*)&As[srow * 32 + scol + 8] = pa1;
        *(uint4*)&Bs[srow * 32 + scol]     = pb0;
        *(uint4*)&Bs[srow * 32 + scol + 8] = pb1;
        if (kt + 1 < nk) {
            bp += 32;
            if (ABF16) { apb += 32; rab[0] = *(const uint4*)apb; rab[1] = *(const uint4*)(apb + 8); }
            else {
                apf += 32;
                #pragma unroll
                for (int i = 0; i < 4; ++i) ra[i] = *(const float4*)(apf + 4 * i);
            }
            #pragma unroll
            for (int i = 0; i < 4; ++i) rb[i] = *(const float4*)(bp + 4 * i);
        }
        __syncthreads();
        bf16x8 a[4], bfr[4];
        #pragma unroll
        for (int m = 0; m < 4; ++m)
            a[m] = *(const bf16x8*)&As[(wr * 64 + m * 16 + fr) * 32 + kc];
        #pragma unroll
        for (int n = 0; n < 4; ++n)
            bfr[n] = *(const bf16x8*)&Bs[(wc * 64 + n * 16 + fr) * 32 + kc];
        #pragma unroll
        for (int m = 0; m < 4; ++m)
            #pragma unroll
            for (int n = 0; n < 4; ++n)
                acc[m][n] = __builtin_amdgcn_mfma_f32_16x16x32_bf16(a[m], bfr[n], acc[m][n], 0, 0, 0);
    }

    const int cr = lane >> 4;
    const int cc = lane & 15;
    #pragma unroll
    for (int n = 0; n < 4; ++n) {
        int gn = bn + wc * 64 + n * 16 + cc;
        if (gn >= N) continue;
        float bv = bias[gn];
        #pragma unroll
        for (int m = 0; m < 4; ++m) {
            int gm0 = bm + wr * 64 + m * 16 + cr * 4;
            #pragma unroll
            for (int r = 0; r < 4; ++r) {
                int gm = gm0 + r;
                if (gm >= M) continue;
                float rowscale = 1.f;
                if (caplen) {
                    int b = gm / Tsteps, tt = gm - b * Tsteps;
                    if (tt >= caplen[b] - 1) rowscale = 0.f;
                }
                float v = (acc[m][n][r] + bv) * rowscale;
                if (CBF16) Cbf[(long)gm * ldc + gn] = f2b(v);
                else       C[(long)gm * ldc + gn] = v;
            }
        }
    }
}

// ---------------- Cooperative mega-kernel: the whole 23-step recurrence ----------------
// grid = 256 wgs x 256 thr. Phases per step, separated by grid.sync():
//  P1 (wg<160): hid+gate MFMA (n0 = wg*16)
//  P2 (wg<64):  att scores + softmax (b = wg)
//  P3 (all):    ctx = (enc^T aw)*gate  (b = wg>>2, d-block = (wg&3)*512; 4-way p-split)
//  P4 (wg<32):  gates GEMM + LSTM pointwise
__global__ __launch_bounds__(256) void step_loop_kernel(
    const u16* __restrict__ xemb, u16* __restrict__ h_bf, float* __restrict__ c,
    const u16* __restrict__ Whg, const float* __restrict__ bhg,
    u16* __restrict__ hid_bf, u16* __restrict__ gv_bf,
    const u16* __restrict__ enc_att_bf, const float* __restrict__ wf, const float* __restrict__ bfull,
    float* __restrict__ aw,
    const u16* __restrict__ enc_bf, u16* __restrict__ ctx_bf,
    const u16* __restrict__ Wg_bf, const float* __restrict__ gbias,
    u16* __restrict__ Hst_bf, float* __restrict__ out_att,
    const int* __restrict__ caplen)
{
    cg::grid_group gg = cg::this_grid();
    __shared__ __align__(16) u16 AsU[64 * 128];   // 16KB (P4)
    __shared__ __align__(16) u16 BsU[64 * 128];   // 16KB (P4)
    __shared__ float GsU[64 * 65];                // 16.6KB (P4)
    __shared__ float attS[P];                     // P2/P3
    __shared__ float red[4];                      // P2
    __shared__ float part[4][512];                // 8KB (P3)

    const int wg = blockIdx.x;
    const int tid = threadIdx.x, lane = tid & 63, v = tid >> 6;

    for (int t = 0; t < TT; ++t) {
        // ---------- P1: hid + beta-gate (wg < 160) ----------
        if (wg < 160) {
            const int n0 = wg * 16;
            const int b0 = v * 16;
            const int row = lane & 15;
            const int k8 = (lane >> 4) * 8;
            const u16* wp = Whg + (long)(n0 + row) * 512 + k8;
            const u16* hp = h_bf + (long)(b0 + row) * 512 + k8;
            f32x4 acc = (f32x4)0.f;
            bf16x8 acur = *(const bf16x8*)wp;
            bf16x8 bcur = *(const bf16x8*)hp;
            #pragma unroll
            for (int kt = 0; kt < 16; ++kt) {
                bf16x8 anx, bnx;
                if (kt < 15) { anx = *(const bf16x8*)(wp + (kt + 1) * 32); bnx = *(const bf16x8*)(hp + (kt + 1) * 32); }
                acc = __builtin_amdgcn_mfma_f32_16x16x32_bf16(acur, bcur, acc, 0, 0, 0);
                acur = anx; bcur = bnx;
            }
            const int nb = n0 + (lane >> 4) * 4;
            const int b  = b0 + (lane & 15);
            #pragma unroll
            for (int r = 0; r < 4; ++r) {
                int n = nb + r;
                float vv = acc[r] + bhg[n];
                if (n < 512) hid_bf[b * AA + n] = f2b(vv);
                else         gv_bf[b * DENC + (n - 512)] = f2b(sigmoidf(vv));
            }
        }
        __threadfence();
        gg.sync();

        // ---------- P2: att scores + softmax (wg < 64) ----------
        if (wg < 64) {
            const int b = wg;
            float hid8[8], wfr[8];
            {
                uint4 hv = *(const uint4*)(hid_bf + b * AA + lane * 8);
                u32 hw[4] = {hv.x, hv.y, hv.z, hv.w};
                #pragma unroll
                for (int q = 0; q < 4; ++q) {
                    hid8[2 * q]     = b2f((u16)hw[q]);
                    hid8[2 * q + 1] = b2f((u16)(hw[q] >> 16));
                }
                float4 w0 = *(const float4*)(wf + lane * 8);
                float4 w1 = *(const float4*)(wf + lane * 8 + 4);
                wfr[0] = w0.x; wfr[1] = w0.y; wfr[2] = w0.z; wfr[3] = w0.w;
                wfr[4] = w1.x; wfr[5] = w1.y; wfr[6] = w1.z; wfr[7] = w1.w;
            }
            const float bf0 = bfull[0];
            #pragma unroll 7
            for (int i = 0; i < 49; ++i) {
                int p = v * 49 + i;
                uint4 e = *(const uint4*)(enc_att_bf + ((long)(b * P + p)) * AA + lane * 8);
                u32 wd[4] = {e.x, e.y, e.z, e.w};
                float s = 0.f;
                #pragma unroll
                for (int q = 0; q < 4; ++q) {
                    float lo = b2f((u16)wd[q]) + hid8[2 * q];
                    float hi = b2f((u16)(wd[q] >> 16)) + hid8[2 * q + 1];
                    lo = lo > 0.f ? lo : 0.f;
                    hi = hi > 0.f ? hi : 0.f;
                    s += lo * wfr[2 * q] + hi * wfr[2 * q + 1];
                }
                s = wave_sum(s);
                if (lane == 0) attS[p] = s + bf0;
            }
            __syncthreads();
            float val = (tid < P) ? attS[tid] : -1e30f;
            float mx = val;
            #pragma unroll
            for (int o = 32; o > 0; o >>= 1) mx = fmaxf(mx, __shfl_xor(mx, o, 64));
            if (lane == 0) red[v] = mx;
            __syncthreads();
            mx = fmaxf(fmaxf(red[0], red[1]), fmaxf(red[2], red[3]));
            float e = (tid < P) ? __expf(val - mx) : 0.f;
            float sw = wave_sum(e);
            __syncthreads();
            if (lane == 0) red[v] = sw;
            __syncthreads();
            float tot = red[0] + red[1] + red[2] + red[3];
            if (tid < P) {
                float a = e / tot;
                aw[b * P + tid] = a;
                out_att[((long)b * TT + t) * P + tid] = (t < caplen[b] - 1) ? a : 0.f;
            }
        }
        __threadfence();
        gg.sync();

        // ---------- P3: ctx (all wgs; b = wg>>2, d-block q = wg&3) ----------
        {
            const int b = wg >> 2, q = wg & 3;
            if (tid < P) attS[tid] = aw[b * P + tid];
            __syncthreads();
            const int pg = tid >> 6;          // 0..3
            const int dsl = tid & 63;         // d-octet
            const int d0 = q * 512 + dsl * 8;
            const u16* ebase = enc_bf + (long)b * P * DENC + d0;
            float a0 = 0.f, a1 = 0.f, a2 = 0.f, a3 = 0.f, a4 = 0.f, a5 = 0.f, a6 = 0.f, a7 = 0.f;
            #pragma unroll 7
            for (int i = 0; i < 49; ++i) {
                int p = pg * 49 + i;
                uint4 e = *(const uint4*)(ebase + (long)p * DENC);
                float s = attS[p];
                a0 += b2f((u16)e.x) * s; a1 += b2f((u16)(e.x >> 16)) * s;
                a2 += b2f((u16)e.y) * s; a3 += b2f((u16)(e.y >> 16)) * s;
                a4 += b2f((u16)e.z) * s; a5 += b2f((u16)(e.z >> 16)) * s;
                a6 += b2f((u16)e.w) * s; a7 += b2f((u16)(e.w >> 16)) * s;
            }
            float* pp = &part[pg][dsl * 8];
            pp[0] = a0; pp[1] = a1; pp[2] = a2; pp[3] = a3;
            pp[4] = a4; pp[5] = a5; pp[6] = a6; pp[7] = a7;
            __syncthreads();
            const int dl = tid * 2;           // 2 d's per thread within 512-block
            float s0 = part[0][dl] + part[1][dl] + part[2][dl] + part[3][dl];
            float s1 = part[0][dl + 1] + part[1][dl + 1] + part[2][dl + 1] + part[3][dl + 1];
            u32 g = *(const u32*)(gv_bf + b * DENC + q * 512 + dl);
            *(u32*)(ctx_bf + (long)b * DENC + q * 512 + dl) = pk2(s0 * b2f((u16)g), s1 * b2f((u16)(g >> 16)));
        }
        __threadfence();
        gg.sync();

        // ---------- P4: gates GEMM + LSTM (wg < 32) ----------
        if (wg < 32) {
            const u16* xemb_t = xemb + (long)t * B * EE;
            f32x4 acc[4];
            #pragma unroll
            for (int m = 0; m < 4; ++m) acc[m] = (f32x4)0.f;

            const int srow = tid >> 2;            // 0..63
            const int se = (tid & 3) * 32;        // k-elem offset within BK=128
            const u16* wsrc = Wg_bf + ((long)wg * 64 + srow) * 3072 + se;

            auto asrcAt = [&](int k0) -> const u16* {
                int k = k0 + se;
                if (k < 512)  return xemb_t + srow * EE + k;
                if (k < 2560) return ctx_bf + srow * DENC + (k - 512);
                return h_bf + srow * HH + (k - 2560);
            };

            uint4 ra[4], rw[4];
            {
                const u16* as = asrcAt(0);
                #pragma unroll
                for (int i = 0; i < 4; ++i) { ra[i] = *(const uint4*)(as + 8 * i); rw[i] = *(const uint4*)(wsrc + 8 * i); }
            }
            const int swz = (srow & 7) << 4;
            for (int kt = 0; kt < 24; ++kt) {
                __syncthreads();
                #pragma unroll
                for (int i = 0; i < 4; ++i) {
                    int cb = se * 2 + i * 16;
                    *(uint4*)((char*)AsU + srow * 256 + (cb ^ swz)) = ra[i];
                    *(uint4*)((char*)BsU + srow * 256 + (cb ^ swz)) = rw[i];
                }
                if (kt + 1 < 24) {
                    int k0n = (kt + 1) * 128;
                    const u16* as = asrcAt(k0n);
                    const u16* ws = wsrc + k0n;
                    #pragma unroll
                    for (int i = 0; i < 4; ++i) { ra[i] = *(const uint4*)(as + 8 * i); rw[i] = *(const uint4*)(ws + 8 * i); }
                }
                __syncthreads();
                #pragma unroll
                for (int kf = 0; kf < 4; ++kf) {
                    int fb = kf * 64 + (lane >> 4) * 16;
                    int rb_ = v * 16 + (lane & 15);
                    bf16x8 bfrag = *(const bf16x8*)((char*)BsU + rb_ * 256 + (fb ^ ((rb_ & 7) << 4)));
                    #pragma unroll
                    for (int m = 0; m < 4; ++m) {
                        int rowa = m * 16 + (lane & 15);
                        bf16x8 afrag = *(const bf16x8*)((char*)AsU + rowa * 256 + (fb ^ ((rowa & 7) << 4)));
                        acc[m] = __builtin_amdgcn_mfma_f32_16x16x32_bf16(afrag, bfrag, acc[m], 0, 0, 0);
                    }
                }
            }
            {
                int r = v * 16 + (lane & 15);
                #pragma unroll
                for (int m = 0; m < 4; ++m) {
                    int brow = m * 16 + (lane >> 4) * 4;
                    #pragma unroll
                    for (int rg = 0; rg < 4; ++rg)
                        GsU[r * 65 + brow + rg] = acc[m][rg];
                }
            }
            __syncthreads();
            const int b = lane;
            #pragma unroll
            for (int i = 0; i < 4; ++i) {
                int jj = v * 4 + i;
                int j = wg * 16 + jj;
                float gi = GsU[jj * 65 + b]        + gbias[j];
                float gf = GsU[(16 + jj) * 65 + b] + gbias[512 + j];
                float gG = GsU[(32 + jj) * 65 + b] + gbias[1024 + j];
                float go = GsU[(48 + jj) * 65 + b] + gbias[1536 + j];
                float cold = c[b * HH + j];
                float cn = sigmoidf(gf) * cold + sigmoidf(gi) * tanhf(gG);
                float hn = sigmoidf(go) * tanhf(cn);
                Hst_bf[((long)b * TT + t) * HH + j] = f2b(hn);
                if (t < caplen[b] - 1) {
                    c[b * HH + j] = cn;
                    h_bf[b * HH + j] = f2b(hn);
                }
            }
        }
        __threadfence();
        gg.sync();
    }
}

// ---------------- meta outputs ----------------
__global__ __launch_bounds__(256) void meta_kernel(const int* __restrict__ cap, const int* __restrict__ caplen,
                                                   float* __restrict__ out_cap, float* __restrict__ out_len) {
    int i = blockIdx.x * 256 + threadIdx.x;
    if (i < B * LL) out_cap[i] = (float)cap[i];
    if (i < B) out_len[i] = (float)(caplen[i] - 1);
}

extern "C" void kernel_launch(void* const* d_in, const int* in_sizes, int n_in,
                              void* d_out, int out_size, void* d_ws, size_t ws_size,
                              hipStream_t stream) {
    const float* enc    = (const float*)d_in[0];
    const int*   cap    = (const int*)d_in[1];
    const int*   caplen = (const int*)d_in[2];
    const float* emb    = (const float*)d_in[3];
    const float* W_enc  = (const float*)d_in[4];
    const float* b_enc  = (const float*)d_in[5];
    const float* W_hid  = (const float*)d_in[6];
    const float* b_hid  = (const float*)d_in[7];
    const float* w_full = (const float*)d_in[8];
    const float* b_full = (const float*)d_in[9];
    const float* W_ih   = (const float*)d_in[10];
    const float* b_ih   = (const float*)d_in[11];
    const float* W_hh   = (const float*)d_in[12];
    const float* b_hh   = (const float*)d_in[13];
    const float* W_h0   = (const float*)d_in[14];
    const float* b_h0   = (const float*)d_in[15];
    const float* W_c0   = (const float*)d_in[16];
    const float* b_c0   = (const float*)d_in[17];
    const float* W_beta = (const float*)d_in[18];
    const float* b_beta = (const float*)d_in[19];
    const float* W_fc   = (const float*)d_in[20];
    const float* b_fc   = (const float*)d_in[21];

    float* out = (float*)d_out;
    float* out_pred = out;                                  // 14,720,000
    float* out_cap  = out + 14720000;                       // 1536
    float* out_len  = out + 14721536;                       // 64
    float* out_att  = out + 14721600;                       // 288,512

    // Scratch inside out_pred (dead until the final vocab GEMM overwrites it):
    u16*   enc_bf = (u16*)out_pred;                         // 12,845,056 fl
    u16*   xemb   = (u16*)(out + 12845056);                 // 376,832 fl
    float* mean   = out + 13221888;                         // 131,072 fl (< 14,720,000)

    float* ws = (float*)d_ws;
    u16*   Wg_bf      = (u16*)ws;                           // 3,145,728 fl
    float* gbias      = ws + 3145728;                       // 2,048
    float* c          = ws + 3147776;                       // 32,768
    u16*   h_bf       = (u16*)(ws + 3180544);               // 16,384 fl
    u16*   ctx_bf     = (u16*)(ws + 3196928);               // 65,536 fl
    u16*   Hst_bf     = (u16*)(ws + 3262464);               // 376,832 fl
    u16*   enc_att_bf = (u16*)(ws + 3639296);               // 3,211,264 fl
    u16*   Whg_bf     = (u16*)(ws + 6850560);               // 655,360 fl
    float* bhg        = ws + 7505920;                       // 2,560
    u16*   hid_bf     = (u16*)(ws + 7508480);               // 16,384 fl
    u16*   gv_bf      = (u16*)(ws + 7524864);               // 65,536 fl
    float* aw         = ws + 7590400;                       // 12,544 -> total 7,602,944 fl (30.4MB)

    // ---- prologue ----
    mean_kernel<<<dim3(DENC / 256, B), 256, 0, stream>>>(enc, mean);
    h0c0_kernel<<<16384, 256, 0, stream>>>(mean, W_h0, b_h0, W_c0, b_c0, c, h_bf);
    prep_kernel<<<4096, 256, 0, stream>>>(enc, W_ih, W_hh, b_ih, b_hh, emb, cap,
                                          W_hid, W_beta, b_hid, b_beta,
                                          enc_bf, Wg_bf, xemb, gbias, Whg_bf, bhg);
    gemm_bf16_kernel<true, true><<<dim3(AA / 128, (B * P) / 128), 256, 0, stream>>>(
        enc_bf, DENC, W_enc, DENC, b_enc, nullptr, enc_att_bf, AA, B * P, AA, DENC, nullptr, 0);
    meta_kernel<<<(B * LL + 255) / 256, 256, 0, stream>>>(cap, caplen, out_cap, out_len);

    // ---- the whole recurrence: ONE cooperative kernel ----
    {
        const u16* xemb_c = xemb; const u16* Whg_c = Whg_bf; const float* bhg_c = bhg;
        const u16* encatt_c = enc_att_bf; const u16* encbf_c = enc_bf;
        const u16* Wg_c = Wg_bf; const float* gbias_c = gbias;
        void* args[] = {
            (void*)&xemb_c, (void*)&h_bf, (void*)&c,
            (void*)&Whg_c, (void*)&bhg_c,
            (void*)&hid_bf, (void*)&gv_bf,
            (void*)&encatt_c, (void*)&w_full, (void*)&b_full,
            (void*)&aw,
            (void*)&encbf_c, (void*)&ctx_bf,
            (void*)&Wg_c, (void*)&gbias_c,
            (void*)&Hst_bf, (void*)&out_att,
            (void*)&caplen
        };
        hipLaunchCooperativeKernel((const void*)step_loop_kernel, dim3(256), dim3(256), args, 0, stream);
    }

    // ---- deferred vocab FC: preds = Hst(1472x512,bf16) @ W_fc(10000x512)^T + b_fc ----
    gemm_bf16_kernel<true, false><<<dim3((VV + 127) / 128, (B * TT + 127) / 128), 256, 0, stream>>>(
        Hst_bf, HH, W_fc, HH, b_fc, out_pred, nullptr, VV, B * TT, VV, HH, caplen, TT);
}

// Round 8
// 4470.968 us; speedup vs baseline: 1.4909x; 1.4909x over previous
//
#include <hip/hip_runtime.h>
#include <hip/hip_bf16.h>

// Sizes (fixed by the problem)
#define B    64
#define P    196      // 14*14
#define DENC 2048
#define AA   512
#define EE   512
#define HH   512
#define VV   10000
#define LL   24
#define TT   23       // L-1

typedef unsigned short u16;
typedef unsigned int   u32;
typedef __bf16 bf16x8 __attribute__((ext_vector_type(8)));
typedef float  f32x4  __attribute__((ext_vector_type(4)));

__device__ __forceinline__ float wave_sum(float v) {
    #pragma unroll
    for (int o = 32; o > 0; o >>= 1) v += __shfl_xor(v, o, 64);
    return v;
}
__device__ __forceinline__ float sigmoidf(float x) {
    return 1.0f / (1.0f + __expf(-x));
}
// RNE fp32 -> bf16
__device__ __forceinline__ u16 f2b(float x) {
    u32 v = __float_as_uint(x); v += 0x7FFFu + ((v >> 16) & 1u); return (u16)(v >> 16);
}
__device__ __forceinline__ float b2f(u16 x) {
    return __uint_as_float(((u32)x) << 16);
}
__device__ __forceinline__ u32 pk2(float x, float y) {
    return (u32)f2b(x) | ((u32)f2b(y) << 16);
}
__device__ __forceinline__ u32 f2h(float x) {
    union { _Float16 h; u16 u; } cv; cv.h = (_Float16)x; return (u32)cv.u;
}
__device__ __forceinline__ void dot2(float& acc, u32 a, u32 b) {
    asm("v_dot2_f32_f16 %0, %1, %2, %0" : "+v"(acc) : "v"(a), "v"(b));
}

// ---------------- mean over P ----------------
__global__ __launch_bounds__(256) void mean_kernel(const float* __restrict__ enc, float* __restrict__ mean) {
    int b = blockIdx.y;
    int d = blockIdx.x * 256 + threadIdx.x;
    const float* e = enc + (long)b * P * DENC + d;
    float s = 0.f;
    #pragma unroll 4
    for (int p = 0; p < P; ++p) s += e[(long)p * DENC];
    mean[b * DENC + d] = s * (1.0f / (float)P);
}

// ---------------- h0/c0 init ----------------
__global__ __launch_bounds__(256) void h0c0_kernel(const float* __restrict__ mean,
                                                   const float* __restrict__ W_h0, const float* __restrict__ b_h0,
                                                   const float* __restrict__ W_c0, const float* __restrict__ b_c0,
                                                   float* __restrict__ c, u16* __restrict__ h_bf0,
                                                   u16* __restrict__ h_hf) {
    int w = blockIdx.x * 4 + (threadIdx.x >> 6);   // 0..65535
    int lane = threadIdx.x & 63;
    int sel = w >> 15;            // 0: h0, 1: c0
    int r = w & 32767;
    int j = r >> 6, b = r & 63;
    const float4* mp = (const float4*)(mean + b * DENC);
    const float4* wp = (const float4*)((sel ? W_c0 : W_h0) + (long)j * DENC);
    float s = 0.f;
    for (int i = lane; i < DENC / 4; i += 64) {
        float4 x = mp[i], y = wp[i];
        s += x.x * y.x + x.y * y.y + x.z * y.z + x.w * y.w;
    }
    s = wave_sum(s);
    if (lane == 0) {
        float v = s + (sel ? b_c0[j] : b_h0[j]);
        if (sel) c[b * HH + j] = v;
        else { h_bf0[b * HH + j] = f2b(v); h_hf[b * HH + j] = (u16)f2h(v); }
    }
}

// ---------------- prologue conversions / rearrangements ----------------
__global__ __launch_bounds__(256) void prep_kernel(
    const float* __restrict__ enc, const float* __restrict__ W_ih, const float* __restrict__ W_hh,
    const float* __restrict__ b_ih, const float* __restrict__ b_hh,
    const float* __restrict__ emb, const int* __restrict__ cap,
    const float* __restrict__ W_hid, const float* __restrict__ W_beta,
    const float* __restrict__ b_hid, const float* __restrict__ b_beta,
    const float* __restrict__ W_enc,
    u16* __restrict__ enc_bf, u16* __restrict__ Wg_bf, u16* __restrict__ xemb, float* __restrict__ gbias,
    u32* __restrict__ Whg_h, float* __restrict__ bhg, u16* __restrict__ W_enc_bf, int* __restrict__ barp)
{
    const long NU_ENC = 3211264;   // 64*196*2048/8
    const long NU_WG  = 786432;    // 2048*3072/8
    const long NU_XE  = 94208;     // 23*64*512/8
    const long NU_GB  = 256;       // 2048/8
    const long NU_WHG = 163840;    // 2560*512/8  (f16)
    const long NU_BHG = 320;       // 2560/8
    const long NU_WE  = 131072;    // 512*2048/8
    const long NU_BAR = 2;
    const long NTOT = NU_ENC + NU_WG + NU_XE + NU_GB + NU_WHG + NU_BHG + NU_WE + NU_BAR;
    long stride = (long)gridDim.x * 256;
    for (long u = (long)blockIdx.x * 256 + threadIdx.x; u < NTOT; u += stride) {
        if (u < NU_ENC) {
            const float* s = enc + u * 8;
            float4 a = *(const float4*)s, bb = *(const float4*)(s + 4);
            ((uint4*)enc_bf)[u] = make_uint4(pk2(a.x, a.y), pk2(a.z, a.w), pk2(bb.x, bb.y), pk2(bb.z, bb.w));
        } else if (u < NU_ENC + NU_WG) {
            long q = u - NU_ENC;
            long rw = q / 384;               // 0..2047 = wgt*32 + r,  r = type*8+jj
            int k8 = (int)(q % 384) * 8;
            int wgt = (int)(rw >> 5), r = (int)(rw & 31);
            int gr = ((r >> 3) << 9) + (wgt << 3) + (r & 7);   // type*512 + wgt*8 + jj
            const float* s = (k8 < 2560) ? (W_ih + (long)gr * 2560 + k8)
                                         : (W_hh + (long)gr * 512 + (k8 - 2560));
            float4 a = *(const float4*)s, bb = *(const float4*)(s + 4);
            ((uint4*)Wg_bf)[q] = make_uint4(pk2(a.x, a.y), pk2(a.z, a.w), pk2(bb.x, bb.y), pk2(bb.z, bb.w));
        } else if (u < NU_ENC + NU_WG + NU_XE) {
            long q = u - NU_ENC - NU_WG;
            int ku = (int)(q & 63);
            int b  = (int)((q >> 6) & 63);
            int t  = (int)(q >> 12);
            int tok = cap[b * LL + t];
            const float* s = emb + (long)tok * EE + ku * 8;
            float4 a = *(const float4*)s, bb = *(const float4*)(s + 4);
            ((uint4*)xemb)[q] = make_uint4(pk2(a.x, a.y), pk2(a.z, a.w), pk2(bb.x, bb.y), pk2(bb.z, bb.w));
        } else if (u < NU_ENC + NU_WG + NU_XE + NU_GB) {
            long q = u - NU_ENC - NU_WG - NU_XE;
            int i0 = (int)q * 8;
            #pragma unroll
            for (int j = 0; j < 8; ++j) gbias[i0 + j] = b_ih[i0 + j] + b_hh[i0 + j];
        } else if (u < NU_ENC + NU_WG + NU_XE + NU_GB + NU_WHG) {
            long q = u - NU_ENC - NU_WG - NU_XE - NU_GB;
            int rw = (int)(q >> 6);          // 0..2559
            int c8 = (int)(q & 63);
            const float* s = (rw < 512) ? (W_hid + (long)rw * HH + c8 * 8)
                                        : (W_beta + (long)(rw - 512) * HH + c8 * 8);
            float4 a = *(const float4*)s, bb = *(const float4*)(s + 4);
            ((uint4*)Whg_h)[q] = make_uint4(f2h(a.x) | (f2h(a.y) << 16), f2h(a.z) | (f2h(a.w) << 16),
                                            f2h(bb.x) | (f2h(bb.y) << 16), f2h(bb.z) | (f2h(bb.w) << 16));
        } else if (u < NU_ENC + NU_WG + NU_XE + NU_GB + NU_WHG + NU_BHG) {
            long q = u - NU_ENC - NU_WG - NU_XE - NU_GB - NU_WHG;
            int i0 = (int)q * 8;
            #pragma unroll
            for (int j = 0; j < 8; ++j) {
                int i = i0 + j;
                bhg[i] = (i < 512) ? b_hid[i] : b_beta[i - 512];
            }
        } else if (u < NU_ENC + NU_WG + NU_XE + NU_GB + NU_WHG + NU_BHG + NU_WE) {
            long q = u - NU_ENC - NU_WG - NU_XE - NU_GB - NU_WHG - NU_BHG;
            const float* s = W_enc + q * 8;
            float4 a = *(const float4*)s, bb = *(const float4*)(s + 4);
            ((uint4*)W_enc_bf)[q] = make_uint4(pk2(a.x, a.y), pk2(a.z, a.w), pk2(bb.x, bb.y), pk2(bb.z, bb.w));
        } else {
            long q = u - (NTOT - NU_BAR);
            #pragma unroll
            for (int j = 0; j < 8; ++j) barp[q * 8 + j] = 0;
        }
    }
}

// ---------------- bf16 MFMA GEMM: C = A(MxK) * B(NxK)^T + bias ----------------
template<bool ABF16, bool BBF16, bool CBF16>
__global__ __launch_bounds__(256) void gemm_bf16_kernel(
    const void* __restrict__ Av, int lda,
    const void* __restrict__ Bv, int ldb,
    const float* __restrict__ bias,
    float* __restrict__ C, u16* __restrict__ Cbf, int ldc,
    int M, int N, int K,
    const int* __restrict__ caplen, int Tsteps)
{
    __shared__ __align__(16) u16 As[128 * 32];
    __shared__ __align__(16) u16 Bs[128 * 32];
    const int tid  = threadIdx.x;
    const int lane = tid & 63;
    const int w    = tid >> 6;
    const int wr   = w >> 1, wc = w & 1;
    const int bm = blockIdx.y * 128;
    const int bn = blockIdx.x * 128;

    f32x4 acc[4][4];
    #pragma unroll
    for (int m = 0; m < 4; ++m)
        #pragma unroll
        for (int n = 0; n < 4; ++n) acc[m][n] = (f32x4)0.f;

    const int srow = tid >> 1;
    const int scol = (tid & 1) * 16;
    long arow = bm + srow; if (arow >= M) arow = M - 1;
    long brow = bn + srow; if (brow >= N) brow = N - 1;
    const float* apf = ABF16 ? nullptr : (const float*)Av + arow * (long)lda + scol;
    const u16*   apb = ABF16 ? (const u16*)Av + arow * (long)lda + scol : nullptr;
    const float* bpf = BBF16 ? nullptr : (const float*)Bv + brow * (long)ldb + scol;
    const u16*   bpb = BBF16 ? (const u16*)Bv + brow * (long)ldb + scol : nullptr;

    float4 ra[4], rb[4];
    uint4  rab[2], rbb[2];
    if (ABF16) { rab[0] = *(const uint4*)apb; rab[1] = *(const uint4*)(apb + 8); }
    else {
        #pragma unroll
        for (int i = 0; i < 4; ++i) ra[i] = *(const float4*)(apf + 4 * i);
    }
    if (BBF16) { rbb[0] = *(const uint4*)bpb; rbb[1] = *(const uint4*)(bpb + 8); }
    else {
        #pragma unroll
        for (int i = 0; i < 4; ++i) rb[i] = *(const float4*)(bpf + 4 * i);
    }

    const int nk = K / 32;
    const int fr = lane & 15;
    const int kc = (lane >> 4) * 8;

    for (int kt = 0; kt < nk; ++kt) {
        uint4 pa0, pa1, pb0, pb1;
        if (ABF16) { pa0 = rab[0]; pa1 = rab[1]; }
        else {
            pa0 = make_uint4(pk2(ra[0].x, ra[0].y), pk2(ra[0].z, ra[0].w), pk2(ra[1].x, ra[1].y), pk2(ra[1].z, ra[1].w));
            pa1 = make_uint4(pk2(ra[2].x, ra[2].y), pk2(ra[2].z, ra[2].w), pk2(ra[3].x, ra[3].y), pk2(ra[3].z, ra[3].w));
        }
        if (BBF16) { pb0 = rbb[0]; pb1 = rbb[1]; }
        else {
            pb0 = make_uint4(pk2(rb[0].x, rb[0].y), pk2(rb[0].z, rb[0].w), pk2(rb[1].x, rb[1].y), pk2(rb[1].z, rb[1].w));
            pb1 = make_uint4(pk2(rb[2].x, rb[2].y), pk2(rb[2].z, rb[2].w), pk2(rb[3].x, rb[3].y), pk2(rb[3].z, rb[3].w));
        }
        __syncthreads();
        *(uint4*)&As[srow * 32 + scol]     = pa0;
        *(uint4*)&As[srow * 32 + scol + 8] = pa1;
        *(uint4*)&Bs[srow * 32 + scol]     = pb0;
        *(uint4*)&Bs[srow * 32 + scol + 8] = pb1;
        if (kt + 1 < nk) {
            if (ABF16) { apb += 32; rab[0] = *(const uint4*)apb; rab[1] = *(const uint4*)(apb + 8); }
            else {
                apf += 32;
                #pragma unroll
                for (int i = 0; i < 4; ++i) ra[i] = *(const float4*)(apf + 4 * i);
            }
            if (BBF16) { bpb += 32; rbb[0] = *(const uint4*)bpb; rbb[1] = *(const uint4*)(bpb + 8); }
            else {
                bpf += 32;
                #pragma unroll
                for (int i = 0; i < 4; ++i) rb[i] = *(const float4*)(bpf + 4 * i);
            }
        }
        __syncthreads();
        bf16x8 a[4], bfr[4];
        #pragma unroll
        for (int m = 0; m < 4; ++m)
            a[m] = *(const bf16x8*)&As[(wr * 64 + m * 16 + fr) * 32 + kc];
        #pragma unroll
        for (int n = 0; n < 4; ++n)
            bfr[n] = *(const bf16x8*)&Bs[(wc * 64 + n * 16 + fr) * 32 + kc];
        #pragma unroll
        for (int m = 0; m < 4; ++m)
            #pragma unroll
            for (int n = 0; n < 4; ++n)
                acc[m][n] = __builtin_amdgcn_mfma_f32_16x16x32_bf16(a[m], bfr[n], acc[m][n], 0, 0, 0);
    }

    const int cr = lane >> 4;
    const int cc = lane & 15;
    #pragma unroll
    for (int n = 0; n < 4; ++n) {
        int gn = bn + wc * 64 + n * 16 + cc;
        if (gn >= N) continue;
        float bv = bias[gn];
        #pragma unroll
        for (int m = 0; m < 4; ++m) {
            int gm0 = bm + wr * 64 + m * 16 + cr * 4;
            #pragma unroll
            for (int r = 0; r < 4; ++r) {
                int gm = gm0 + r;
                if (gm >= M) continue;
                float rowscale = 1.f;
                if (caplen) {
                    int b = gm / Tsteps, tt = gm - b * Tsteps;
                    if (tt >= caplen[b] - 1) rowscale = 0.f;
                }
                float v = (acc[m][n][r] + bv) * rowscale;
                if (CBF16) Cbf[(long)gm * ldc + gn] = f2b(v);
                else       C[(long)gm * ldc + gn] = v;
            }
        }
    }
}

// ---------------- custom grid barrier (monotonic counter, agent scope) ----------------
__device__ __forceinline__ void gbar(int* cnt, int* gen, int nwg, int& bar_no) {
    __syncthreads();
    if (threadIdx.x == 0) {
        int prev = __hip_atomic_fetch_add(cnt, 1, __ATOMIC_ACQ_REL, __HIP_MEMORY_SCOPE_AGENT);
        if (prev == bar_no * nwg + (nwg - 1)) {
            __hip_atomic_store(gen, bar_no + 1, __ATOMIC_RELEASE, __HIP_MEMORY_SCOPE_AGENT);
        } else {
            while (__hip_atomic_load(gen, __ATOMIC_RELAXED, __HIP_MEMORY_SCOPE_AGENT) <= bar_no)
                __builtin_amdgcn_s_sleep(4);
            (void)__hip_atomic_load(gen, __ATOMIC_ACQUIRE, __HIP_MEMORY_SCOPE_AGENT);
        }
    }
    bar_no += 1;
    __syncthreads();
}

// ---------------- persistent recurrence: 64 wgs (wg = b), 2 barriers/step ----------------
__global__ __launch_bounds__(256) void step_loop_kernel(
    const u16* __restrict__ xemb, u16* __restrict__ hbuf0, u16* __restrict__ hbuf1,
    u16* __restrict__ h_hf, float* __restrict__ c,
    const u32* __restrict__ Whg_h, const float* __restrict__ bhg,
    const u16* __restrict__ enc_att_bf, const float* __restrict__ wf, const float* __restrict__ bfull,
    const u16* __restrict__ enc_bf, u16* __restrict__ ctx_bf,
    const u16* __restrict__ Wg_bf, const float* __restrict__ gbias,
    u16* __restrict__ Hst_bf, float* __restrict__ out_att,
    const int* __restrict__ caplen, int* __restrict__ bar)
{
    __shared__ u32 hH[256];                       // h (f16 pairs) for this b
    __shared__ float hidS[512];
    __shared__ float gvS[2048];
    __shared__ float attS[256];
    __shared__ float red[4];
    __shared__ float part[4][2048];               // 32KB
    __shared__ __align__(16) u16 Xs[64 * 128];    // 16KB (phase B)
    __shared__ __align__(16) u16 Ws[32 * 128];    // 8KB  (phase B)
    __shared__ float Gs[32 * 65];                 // 8.3KB

    const int wg = blockIdx.x;
    const int tid = threadIdx.x, lane = tid & 63, v = tid >> 6;
    const int b = wg;
    int bar_no = 0;
    int* cnt = bar;
    int* gen = bar + 1;
    const int cl_b = caplen[b];

    for (int t = 0; t < TT; ++t) {
        const u16* hcur = (t & 1) ? hbuf1 : hbuf0;
        u16*       hnew = (t & 1) ? hbuf0 : hbuf1;

        // ================= Phase A (b-local) =================
        hH[tid] = ((const u32*)h_hf)[b * 256 + tid];
        __syncthreads();

        // A1: hid(512) + gv(2048) matvec via v_dot2_f32_f16; thread owns rows tid*10..+10
        {
            float acc[10];
            #pragma unroll
            for (int r = 0; r < 10; ++r) acc[r] = 0.f;
            const u32* wr = Whg_h + (long)tid * 10 * 256;
            for (int kc2 = 0; kc2 < 256; kc2 += 4) {
                u32 h0 = hH[kc2], h1 = hH[kc2 + 1], h2 = hH[kc2 + 2], h3 = hH[kc2 + 3];
                #pragma unroll
                for (int r = 0; r < 10; ++r) {
                    uint4 w4 = *(const uint4*)(wr + r * 256 + kc2);
                    dot2(acc[r], w4.x, h0);
                    dot2(acc[r], w4.y, h1);
                    dot2(acc[r], w4.z, h2);
                    dot2(acc[r], w4.w, h3);
                }
            }
            #pragma unroll
            for (int r = 0; r < 10; ++r) {
                int row = tid * 10 + r;
                float vv = acc[r] + bhg[row];
                if (row < 512) hidS[row] = vv;
                else           gvS[row - 512] = sigmoidf(vv);
            }
        }
        __syncthreads();

        // A2a: att scores (wave-dot; wave v owns 49 p's)
        {
            float hid8[8], wfr[8];
            #pragma unroll
            for (int i = 0; i < 8; ++i) { hid8[i] = hidS[lane * 8 + i]; wfr[i] = wf[lane * 8 + i]; }
            const float bf0 = bfull[0];
            #pragma unroll 7
            for (int i = 0; i < 49; ++i) {
                int p = v * 49 + i;
                uint4 e = *(const uint4*)(enc_att_bf + ((long)(b * P + p)) * AA + lane * 8);
                u32 wd[4] = {e.x, e.y, e.z, e.w};
                float s = 0.f;
                #pragma unroll
                for (int q = 0; q < 4; ++q) {
                    float lo = b2f((u16)wd[q]) + hid8[2 * q];
                    float hi = b2f((u16)(wd[q] >> 16)) + hid8[2 * q + 1];
                    lo = lo > 0.f ? lo : 0.f;
                    hi = hi > 0.f ? hi : 0.f;
                    s += lo * wfr[2 * q] + hi * wfr[2 * q + 1];
                }
                s = wave_sum(s);
                if (lane == 0) attS[p] = s + bf0;
            }
        }
        __syncthreads();

        // softmax over 196 -> attS holds aw; out_att written
        {
            float val = (tid < P) ? attS[tid] : -1e30f;
            float mx = val;
            #pragma unroll
            for (int o = 32; o > 0; o >>= 1) mx = fmaxf(mx, __shfl_xor(mx, o, 64));
            if (lane == 0) red[v] = mx;
            __syncthreads();
            mx = fmaxf(fmaxf(red[0], red[1]), fmaxf(red[2], red[3]));
            float e = (tid < P) ? __expf(val - mx) : 0.f;
            float sw = wave_sum(e);
            __syncthreads();
            if (lane == 0) red[v] = sw;
            __syncthreads();
            float tot = red[0] + red[1] + red[2] + red[3];
            __syncthreads();
            if (tid < P) {
                float a = e / tot;
                attS[tid] = a;
                out_att[((long)b * TT + t) * P + tid] = (t < cl_b - 1) ? a : 0.f;
            }
        }
        __syncthreads();

        // A2b: ctx partials — pg = tid>>6 owns 49 p's; dsl = tid&63 owns 8 d per dblk
        {
            const int pg = tid >> 6, dsl = tid & 63;
            float a[4][8];
            #pragma unroll
            for (int k = 0; k < 4; ++k)
                #pragma unroll
                for (int j = 0; j < 8; ++j) a[k][j] = 0.f;
            const u16* eb = enc_bf + (long)b * P * DENC + dsl * 8;
            for (int i = 0; i < 49; ++i) {
                int p = pg * 49 + i;
                float s = attS[p];
                #pragma unroll
                for (int dblk = 0; dblk < 4; ++dblk) {
                    uint4 e = *(const uint4*)(eb + (long)p * DENC + dblk * 512);
                    a[dblk][0] += b2f((u16)e.x) * s; a[dblk][1] += b2f((u16)(e.x >> 16)) * s;
                    a[dblk][2] += b2f((u16)e.y) * s; a[dblk][3] += b2f((u16)(e.y >> 16)) * s;
                    a[dblk][4] += b2f((u16)e.z) * s; a[dblk][5] += b2f((u16)(e.z >> 16)) * s;
                    a[dblk][6] += b2f((u16)e.w) * s; a[dblk][7] += b2f((u16)(e.w >> 16)) * s;
                }
            }
            #pragma unroll
            for (int dblk = 0; dblk < 4; ++dblk)
                #pragma unroll
                for (int j = 0; j < 8; ++j)
                    part[pg][dblk * 512 + dsl * 8 + j] = a[dblk][j];
        }
        __syncthreads();

        // A2c: reduce partials, apply gate, store ctx
        {
            int d = tid * 8;
            float s[8];
            #pragma unroll
            for (int j = 0; j < 8; ++j)
                s[j] = part[0][d + j] + part[1][d + j] + part[2][d + j] + part[3][d + j];
            uint4 o;
            o.x = pk2(s[0] * gvS[d + 0], s[1] * gvS[d + 1]);
            o.y = pk2(s[2] * gvS[d + 2], s[3] * gvS[d + 3]);
            o.z = pk2(s[4] * gvS[d + 4], s[5] * gvS[d + 5]);
            o.w = pk2(s[6] * gvS[d + 6], s[7] * gvS[d + 7]);
            *(uint4*)(ctx_bf + (long)b * DENC + d) = o;
        }

        gbar(cnt, gen, B, bar_no);   // publish ctx

        // ================= Phase B (weight-stationary: wg owns 32 gate rows) =================
        {
            const u16* xemb_t = xemb + (long)t * B * EE;
            f32x4 acc[2];
            acc[0] = (f32x4)0.f; acc[1] = (f32x4)0.f;

            const int sb = tid >> 2, se = (tid & 3) * 32;           // X staging
            const int srw = tid >> 3, sk = (tid & 7) * 16;          // W staging
            const u16* wsrc = Wg_bf + ((long)wg * 32 + srw) * 3072 + sk;

            auto asrcAt = [&](int k0) -> const u16* {
                int k = k0 + se;
                if (k < 512)  return xemb_t + sb * EE + k;
                if (k < 2560) return ctx_bf + sb * DENC + (k - 512);
                return hcur + sb * HH + (k - 2560);
            };

            uint4 ra[4], rw2[2];
            {
                const u16* as = asrcAt(0);
                #pragma unroll
                for (int i = 0; i < 4; ++i) ra[i] = *(const uint4*)(as + 8 * i);
                rw2[0] = *(const uint4*)wsrc;
                rw2[1] = *(const uint4*)(wsrc + 8);
            }
            const int swzX = (sb & 7) << 4;
            const int swzW = (srw & 7) << 4;
            for (int kt = 0; kt < 24; ++kt) {
                __syncthreads();
                #pragma unroll
                for (int i = 0; i < 4; ++i) {
                    int cb = se * 2 + i * 16;
                    *(uint4*)((char*)Xs + sb * 256 + (cb ^ swzX)) = ra[i];
                }
                #pragma unroll
                for (int i = 0; i < 2; ++i) {
                    int cb = sk * 2 + i * 16;
                    *(uint4*)((char*)Ws + srw * 256 + (cb ^ swzW)) = rw2[i];
                }
                if (kt + 1 < 24) {
                    int k0n = (kt + 1) * 128;
                    const u16* as = asrcAt(k0n);
                    #pragma unroll
                    for (int i = 0; i < 4; ++i) ra[i] = *(const uint4*)(as + 8 * i);
                    rw2[0] = *(const uint4*)(wsrc + k0n);
                    rw2[1] = *(const uint4*)(wsrc + k0n + 8);
                }
                __syncthreads();
                #pragma unroll
                for (int kf = 0; kf < 4; ++kf) {
                    int fb = kf * 64 + (lane >> 4) * 16;
                    int rbW = (v & 1) * 16 + (lane & 15);
                    bf16x8 bfrag = *(const bf16x8*)((char*)Ws + rbW * 256 + (fb ^ ((rbW & 7) << 4)));
                    #pragma unroll
                    for (int m = 0; m < 2; ++m) {
                        int ba = (v >> 1) * 32 + m * 16 + (lane & 15);
                        bf16x8 afrag = *(const bf16x8*)((char*)Xs + ba * 256 + (fb ^ ((ba & 7) << 4)));
                        acc[m] = __builtin_amdgcn_mfma_f32_16x16x32_bf16(afrag, bfrag, acc[m], 0, 0, 0);
                    }
                }
            }
            {
                int r = (v & 1) * 16 + (lane & 15);
                #pragma unroll
                for (int m = 0; m < 2; ++m) {
                    int bc = (v >> 1) * 32 + m * 16 + (lane >> 4) * 4;
                    #pragma unroll
                    for (int rg = 0; rg < 4; ++rg)
                        Gs[r * 65 + bc + rg] = acc[m][rg];
                }
            }
            __syncthreads();
            // LSTM pointwise: thread -> b2 = tid&63, q4 = tid>>6; jj = q4*2 + i
            {
                const int b2 = tid & 63, q4 = tid >> 6;
                const int cl2 = caplen[b2];
                #pragma unroll
                for (int i = 0; i < 2; ++i) {
                    int jj = q4 * 2 + i;
                    int j = wg * 8 + jj;
                    float gi = Gs[(jj)      * 65 + b2] + gbias[j];
                    float gf = Gs[(8 + jj)  * 65 + b2] + gbias[512 + j];
                    float gg = Gs[(16 + jj) * 65 + b2] + gbias[1024 + j];
                    float go = Gs[(24 + jj) * 65 + b2] + gbias[1536 + j];
                    float cold = c[b2 * HH + j];
                    float hold = b2f(hcur[b2 * HH + j]);
                    float cn = sigmoidf(gf) * cold + sigmoidf(gi) * tanhf(gg);
                    float hn = sigmoidf(go) * tanhf(cn);
                    Hst_bf[((long)b2 * TT + t) * HH + j] = f2b(hn);
                    bool mask = (t < cl2 - 1);
                    float hsel = mask ? hn : hold;
                    float csel = mask ? cn : cold;
                    hnew[b2 * HH + j] = f2b(hsel);
                    h_hf[b2 * HH + j] = (u16)f2h(hsel);
                    c[b2 * HH + j] = csel;
                }
            }
        }

        gbar(cnt, gen, B, bar_no);   // publish h
    }
}

// ---------------- meta outputs ----------------
__global__ __launch_bounds__(256) void meta_kernel(const int* __restrict__ cap, const int* __restrict__ caplen,
                                                   float* __restrict__ out_cap, float* __restrict__ out_len) {
    int i = blockIdx.x * 256 + threadIdx.x;
    if (i < B * LL) out_cap[i] = (float)cap[i];
    if (i < B) out_len[i] = (float)(caplen[i] - 1);
}

extern "C" void kernel_launch(void* const* d_in, const int* in_sizes, int n_in,
                              void* d_out, int out_size, void* d_ws, size_t ws_size,
                              hipStream_t stream) {
    const float* enc    = (const float*)d_in[0];
    const int*   cap    = (const int*)d_in[1];
    const int*   caplen = (const int*)d_in[2];
    const float* emb    = (const float*)d_in[3];
    const float* W_enc  = (const float*)d_in[4];
    const float* b_enc  = (const float*)d_in[5];
    const float* W_hid  = (const float*)d_in[6];
    const float* b_hid  = (const float*)d_in[7];
    const float* w_full = (const float*)d_in[8];
    const float* b_full = (const float*)d_in[9];
    const float* W_ih   = (const float*)d_in[10];
    const float* b_ih   = (const float*)d_in[11];
    const float* W_hh   = (const float*)d_in[12];
    const float* b_hh   = (const float*)d_in[13];
    const float* W_h0   = (const float*)d_in[14];
    const float* b_h0   = (const float*)d_in[15];
    const float* W_c0   = (const float*)d_in[16];
    const float* b_c0   = (const float*)d_in[17];
    const float* W_beta = (const float*)d_in[18];
    const float* b_beta = (const float*)d_in[19];
    const float* W_fc   = (const float*)d_in[20];
    const float* b_fc   = (const float*)d_in[21];

    float* out = (float*)d_out;
    float* out_pred = out;                                  // 14,720,000
    float* out_cap  = out + 14720000;                       // 1536
    float* out_len  = out + 14721536;                       // 64
    float* out_att  = out + 14721600;                       // 288,512

    // Scratch inside out_pred (dead until the final vocab GEMM overwrites it):
    u16*   enc_bf   = (u16*)out_pred;                       // 12,845,056 fl
    u16*   xemb     = (u16*)(out + 12845056);               // 376,832 fl
    float* mean     = out + 13221888;                       // 131,072 fl
    u16*   W_enc_bf = (u16*)(out + 13352960);               // 524,288 fl  (ends 13,877,248 < 14,720,000)

    float* ws = (float*)d_ws;
    u16*   Wg_bf      = (u16*)ws;                           // 3,145,728 fl
    float* gbias      = ws + 3145728;                       // 2,048
    float* c          = ws + 3147776;                       // 32,768
    u16*   hbuf0      = (u16*)(ws + 3180544);               // 16,384 fl
    u16*   hbuf1      = (u16*)(ws + 3196928);               // 16,384 fl
    u16*   h_hf       = (u16*)(ws + 3213312);               // 16,384 fl
    u16*   ctx_bf     = (u16*)(ws + 3229696);               // 65,536 fl
    u16*   Hst_bf     = (u16*)(ws + 3295232);               // 376,832 fl
    u16*   enc_att_bf = (u16*)(ws + 3672064);               // 3,211,264 fl
    u32*   Whg_h      = (u32*)(ws + 6883328);               // 655,360 fl
    float* bhg        = ws + 7538688;                       // 2,560
    int*   bar        = (int*)(ws + 7541248);               // 16 ints -> total 7,541,264 fl (30.2MB)

    // ---- prologue ----
    mean_kernel<<<dim3(DENC / 256, B), 256, 0, stream>>>(enc, mean);
    h0c0_kernel<<<16384, 256, 0, stream>>>(mean, W_h0, b_h0, W_c0, b_c0, c, hbuf0, h_hf);
    prep_kernel<<<4096, 256, 0, stream>>>(enc, W_ih, W_hh, b_ih, b_hh, emb, cap,
                                          W_hid, W_beta, b_hid, b_beta, W_enc,
                                          enc_bf, Wg_bf, xemb, gbias, Whg_h, bhg, W_enc_bf, bar);
    gemm_bf16_kernel<true, true, true><<<dim3(AA / 128, (B * P) / 128), 256, 0, stream>>>(
        enc_bf, DENC, W_enc_bf, DENC, b_enc, nullptr, enc_att_bf, AA, B * P, AA, DENC, nullptr, 0);
    meta_kernel<<<(B * LL + 255) / 256, 256, 0, stream>>>(cap, caplen, out_cap, out_len);

    // ---- recurrence: one persistent kernel, custom barriers ----
    {
        const u16* xemb_c = xemb; const u32* Whg_c = Whg_h; const float* bhg_c = bhg;
        const u16* encatt_c = enc_att_bf; const u16* encbf_c = enc_bf;
        const u16* Wg_c = Wg_bf; const float* gbias_c = gbias;
        void* args[] = {
            (void*)&xemb_c, (void*)&hbuf0, (void*)&hbuf1,
            (void*)&h_hf, (void*)&c,
            (void*)&Whg_c, (void*)&bhg_c,
            (void*)&encatt_c, (void*)&w_full, (void*)&b_full,
            (void*)&encbf_c, (void*)&ctx_bf,
            (void*)&Wg_c, (void*)&gbias_c,
            (void*)&Hst_bf, (void*)&out_att,
            (void*)&caplen, (void*)&bar
        };
        hipLaunchCooperativeKernel((const void*)step_loop_kernel, dim3(B), dim3(256), args, 0, stream);
    }

    // ---- deferred vocab FC: preds = Hst(1472x512,bf16) @ W_fc(10000x512)^T + b_fc ----
    gemm_bf16_kernel<true, false, false><<<dim3((VV + 127) / 128, (B * TT + 127) / 128), 256, 0, stream>>>(
        Hst_bf, HH, W_fc, HH, b_fc, out_pred, nullptr, VV, B * TT, VV, HH, caplen, TT);
}